// Round 11
// baseline (6954.209 us; speedup 1.0000x reference)
//
#include <hip/hip_runtime.h>
#include <cstdint>
#include <cstddef>

// Problem constants
#define B_   16
#define T_   2000
#define NIN  512
#define U_   512
#define G4   2048      // 4*U
#define KP   1024      // packed K (interleaved: k' = 2*u + plane)
#define JP   4096      // packed output cols (real plane | imag plane)
#define M_   32000     // B*T
#define NGRP 8         // scan groups
#define MPG  32        // members per group
#define SCAN_BLOCKS (NGRP * MPG)
#define LDSROW 2112    // lds_h row stride (row 1 shifted to banks 16..31)

typedef __attribute__((ext_vector_type(8))) short bf16x8;
typedef __attribute__((ext_vector_type(4))) float f32x4;
typedef __attribute__((ext_vector_type(2))) int i32x2;

#define MFMA(a, b, c) __builtin_amdgcn_mfma_f32_16x16x32_bf16((a), (b), (c), 0, 0, 0)

__device__ __forceinline__ unsigned short f2bf(float f) {
  unsigned u = __builtin_bit_cast(unsigned, f);
  u = (u + 0x7FFFu + ((u >> 16) & 1u)) >> 16;
  return (unsigned short)u;
}
__device__ __forceinline__ float bf2f(unsigned short h) {
  unsigned u = ((unsigned)h) << 16;
  return __builtin_bit_cast(float, u);
}
__device__ __forceinline__ float sigm(float x) {
  return 1.0f / (1.0f + __expf(-x));
}
__device__ __forceinline__ float tanh_f(float x) {
  float cx = fminf(fmaxf(x, -15.0f), 15.0f);
  float e = __expf(2.0f * cx);
  return (e - 1.0f) / (e + 1.0f);
}

// --- L3-point (coherence point) accessors, rule-#18 hardened: loads and
// their s_waitcnt live in ONE asm block (dest VGPRs valid at exit) +
// sched_barrier so register-only consumers can't be hoisted into the shadow.
__device__ __forceinline__ void ld32_l3_sync(const void* p, uint4& a, uint4& b) {
  asm volatile("global_load_dwordx4 %0, %2, off sc0 sc1\n\t"
               "global_load_dwordx4 %1, %3, off sc0 sc1\n\t"
               "s_waitcnt vmcnt(0)"
               : "=&v"(a), "=&v"(b)
               : "v"(p), "v"((const void*)((const char*)p + 16))
               : "memory");
  __builtin_amdgcn_sched_barrier(0);
}
__device__ __forceinline__ void st8_l3(void* p, i32x2 v) {
  asm volatile("global_store_dwordx2 %0, %1, off sc0 sc1" :: "v"(p), "v"(v) : "memory");
}

// ---------------------------------------------------------------------------
// Convert x fp32 [M,512]x2 -> packed A' bf16 [M,1024], k' = 2n+pl interleave.
// ---------------------------------------------------------------------------
__global__ __launch_bounds__(256) void k_convert_x(const float* __restrict__ xr,
                                                   const float* __restrict__ xi,
                                                   unsigned short* __restrict__ Ab) {
  int i = blockIdx.x * 256 + threadIdx.x;
  int m = i >> 6;
  int k0 = (i & 63) << 3;  // n-base, 8 per thread
  if (m >= M_) return;
  const float* pr = xr + (size_t)m * NIN + k0;
  const float* pi = xi + (size_t)m * NIN + k0;
  float4 r0 = *reinterpret_cast<const float4*>(pr);
  float4 r1 = *reinterpret_cast<const float4*>(pr + 4);
  float4 i0 = *reinterpret_cast<const float4*>(pi);
  float4 i1 = *reinterpret_cast<const float4*>(pi + 4);
  uint4 v0, v1;
  v0.x = f2bf(r0.x) | ((unsigned)f2bf(i0.x) << 16);
  v0.y = f2bf(r0.y) | ((unsigned)f2bf(i0.y) << 16);
  v0.z = f2bf(r0.z) | ((unsigned)f2bf(i0.z) << 16);
  v0.w = f2bf(r0.w) | ((unsigned)f2bf(i0.w) << 16);
  v1.x = f2bf(r1.x) | ((unsigned)f2bf(i1.x) << 16);
  v1.y = f2bf(r1.y) | ((unsigned)f2bf(i1.y) << 16);
  v1.z = f2bf(r1.z) | ((unsigned)f2bf(i1.z) << 16);
  v1.w = f2bf(r1.w) | ((unsigned)f2bf(i1.w) << 16);
  unsigned short* dst = Ab + (size_t)m * KP + 2 * k0;
  *reinterpret_cast<uint4*>(dst) = v0;
  *reinterpret_cast<uint4*>(dst + 8) = v1;
}

// ---------------------------------------------------------------------------
// Pack complex weight [512,2048] into Bt bf16 [4096][1024], k' = 2u+pl.
// ---------------------------------------------------------------------------
__global__ __launch_bounds__(256) void k_pack_B(const float* __restrict__ Wr,
                                                const float* __restrict__ Wi,
                                                unsigned short* __restrict__ Bt) {
  int i = blockIdx.x * 256 + threadIdx.x;
  if (i >= JP * KP) return;
  int jp = i >> 10;
  int k = i & 1023;
  int p = jp >> 11;
  int j = jp & 2047;
  int u = k >> 1;
  int pl = k & 1;
  float v;
  if (p == 0) {
    v = pl ? -Wi[(size_t)u * G4 + j] : Wr[(size_t)u * G4 + j];
  } else {
    v = pl ? Wr[(size_t)u * G4 + j] : Wi[(size_t)u * G4 + j];
  }
  Bt[i] = f2bf(v);
}

// ---------------------------------------------------------------------------
// zx GEMM: A'[32000,1024] bf16 @ Bt[4096,1024]^T -> zx bf16 [T][B][2048][2]
// ---------------------------------------------------------------------------
__global__ __launch_bounds__(256) void k_gemm_zx(const unsigned short* __restrict__ A,
                                                 const unsigned short* __restrict__ Bt,
                                                 unsigned short* __restrict__ zx) {
  int bid = blockIdx.x;
  int nt = bid & 31;
  int mt = bid >> 5;
  int tid = threadIdx.x;
  int lane = tid & 63;
  int wid = tid >> 6;
  int wm = wid >> 1, wn = wid & 1;
  int l15 = lane & 15;
  int kb = (lane >> 4) << 3;
  int rowb = mt * 128 + wm * 64;
  int colb = nt * 128 + wn * 64;

  const unsigned short* ap[4];
  const unsigned short* bp[4];
#pragma unroll
  for (int x = 0; x < 4; ++x) {
    ap[x] = A + (size_t)(rowb + x * 16 + l15) * KP + kb;
    bp[x] = Bt + (size_t)(colb + x * 16 + l15) * KP + kb;
  }

  f32x4 acc[4][4];
#pragma unroll
  for (int mi = 0; mi < 4; ++mi)
#pragma unroll
    for (int ni = 0; ni < 4; ++ni) acc[mi][ni] = (f32x4){0.f, 0.f, 0.f, 0.f};

#pragma unroll 2
  for (int k = 0; k < KP; k += 32) {
    bf16x8 av[4], bv[4];
#pragma unroll
    for (int x = 0; x < 4; ++x) {
      av[x] = *reinterpret_cast<const bf16x8*>(ap[x] + k);
      bv[x] = *reinterpret_cast<const bf16x8*>(bp[x] + k);
    }
#pragma unroll
    for (int mi = 0; mi < 4; ++mi)
#pragma unroll
      for (int ni = 0; ni < 4; ++ni)
        acc[mi][ni] = MFMA(av[mi], bv[ni], acc[mi][ni]);
  }

  int rq = (lane >> 4) << 2;
#pragma unroll
  for (int mi = 0; mi < 4; ++mi) {
#pragma unroll
    for (int r = 0; r < 4; ++r) {
      int m = rowb + mi * 16 + rq + r;
      int bbv = m / T_;
      int tv = m - bbv * T_;
      size_t rowoff = (size_t)(tv * 16 + bbv) * (G4 * 2);
#pragma unroll
      for (int ni = 0; ni < 4; ++ni) {
        int jp2 = colb + ni * 16 + l15;
        int p = jp2 >> 11;
        int j = jp2 & 2047;
        zx[rowoff + (size_t)j * 2 + p] = f2bf(acc[mi][ni][r]);
      }
    }
  }
}

// ---------------------------------------------------------------------------
// Persistent scan v11 = v8 protocol, 4-wave CU shape.
// 256 blocks x 256 threads (4 waves, 1/SIMD). Wave w owns 32 jp-rows = two
// 16-row column blocks cb (combo c = w*2+cb, p=c>>2, q=c&3). Each A-fragment
// ds_read_b128 feeds TWO MFMAs (cb=0,1) -> LDS reads/CU/step halve (256->128;
// per m134 ~12cy each this was the hidden serial sink). uf[2][32] = 256 VGPR,
// pinned. MFMA count unchanged (4x64). Pollers = all 256 threads (v8 32B
// mapping); gate = tid<32 (R10: gate-in-pollers is neutral). Continuous poll
// (no s_sleep). Tag-fused barrier identical to v8.
// ---------------------------------------------------------------------------
__global__ __launch_bounds__(256, 1) void k_scan(
    const unsigned short* __restrict__ zx,
    const unsigned short* __restrict__ Ub,
    const float* __restrict__ brp,
    const float* __restrict__ bip,
    char* __restrict__ hb2,   // [NGRP][2 par][1024 records][8B]
    float* __restrict__ out) {
  const int bid = blockIdx.x;
  const int tid = threadIdx.x;
  const int lane = tid & 63;
  const int w = tid >> 6;      // wave 0..3
  const int l15 = lane & 15;
  const int g = bid & 7;
  const int m = bid >> 3;

  __shared__ char lds_h[2 * LDSROW];  // [2 batch rows][2048B h], stride 2112
  __shared__ float zp[2][132];        // z exchange [batch][combo*16+row]

  // ---- U fragments: wave w, col-block cb -> combo c=w*2+cb (p=c>>2,q=c&3),
  //      16 units each; uf[cb][kk], 64 frags = 256 VGPR, pinned ----
  bf16x8 uf0[32], uf1[32];
  {
    const int c0 = w * 2, c1 = w * 2 + 1;
    const unsigned short* up0 =
        Ub + (size_t)((c0 >> 2) * 2048 + (c0 & 3) * 512 + m * 16 + l15) * KP +
        ((lane >> 4) << 3);
    const unsigned short* up1 =
        Ub + (size_t)((c1 >> 2) * 2048 + (c1 & 3) * 512 + m * 16 + l15) * KP +
        ((lane >> 4) << 3);
#pragma unroll
    for (int kk = 0; kk < 32; ++kk) {
      uf0[kk] = *reinterpret_cast<const bf16x8*>(up0 + kk * 32);
      uf1[kk] = *reinterpret_cast<const bf16x8*>(up1 + kk * 32);
    }
#pragma unroll
    for (int kk = 0; kk < 32; ++kk) {
      asm volatile("" : "+v"(uf0[kk]));
      asm volatile("" : "+v"(uf1[kk]));
    }
  }

  // ---- gate mapping (threads 0..31 of wave 0) ----
  const int gb = tid >> 4;        // local batch 0..1
  const int gu = tid & 15;        // local unit 0..15
  const int u = m * 16 + gu;      // global unit
  const int bglob = g * 2 + gb;   // global batch
  float brg[4], big[4];
  if (tid < 32) {
#pragma unroll
    for (int q = 0; q < 4; ++q) {
      brg[q] = brp[q * 512 + u];
      big[q] = bip[q * 512 + u];
    }
  }
  float cr = 0.f, ci = 0.f;

  char* hgrp = hb2 + (size_t)g * 16384;

  // ---- stager mapping: all 256 threads, 32B = records 4*tid..4*tid+3 ----
  const int srow = tid >> 7;            // batch row 0..1
  const int sbyte = (tid & 127) * 16;   // LDS byte offset in row

  // ---- A-fragment read addressing (conflict-free: rows split banks) ----
  const int arow = (l15 & 1) * LDSROW;
  const int achunk = (lane >> 4) * 16;

  // ---- zx prologue (1-step-ahead prefetch) ----
  unsigned zprev[4];
  if (tid < 32) {
    const unsigned* zt = (const unsigned*)zx + (size_t)bglob * 2048;
#pragma unroll
    for (int q = 0; q < 4; ++q) zprev[q] = zt[q * 512 + u];
  }

  for (int t = 0; t < T_; ++t) {
    const int par = t & 1;

    // ---- stage: poll own 32B (4 records) until tags >= t; poll IS load ----
    {
      const char* src = hgrp + par * 8192 + tid * 32;
      uint4 v0, v1;
      for (;;) {
        ld32_l3_sync(src, v0, v1);   // data valid at return (rule #18)
        if ((int)v0.y >= t && (int)v0.w >= t &&
            (int)v1.y >= t && (int)v1.w >= t) break;
      }
      uint4 hq;
      hq.x = v0.x;
      hq.y = v0.z;
      hq.z = v1.x;
      hq.w = v1.z;
      *reinterpret_cast<uint4*>(lds_h + srow * LDSROW + sbyte) = hq;
    }
    __syncthreads();

    // ---- consume z(t); issue z(t+1) early ----
    unsigned zloc[4];
    if (tid < 32) {
#pragma unroll
      for (int q = 0; q < 4; ++q) zloc[q] = zprev[q];
      int tp = t + 1 < T_ ? t + 1 : t;
      const unsigned* zt = (const unsigned*)zx + (size_t)(tp * 16 + bglob) * 2048;
#pragma unroll
      for (int q = 0; q < 4; ++q) zprev[q] = zt[q * 512 + u];
    }

    // ---- MFMA: 32 shared A-reads, each feeding 2 col-blocks (4 chains) ----
    f32x4 a0 = {0.f, 0.f, 0.f, 0.f};   // cb0, even kk
    f32x4 a1 = {0.f, 0.f, 0.f, 0.f};   // cb0, odd kk
    f32x4 a2 = {0.f, 0.f, 0.f, 0.f};   // cb1, even kk
    f32x4 a3 = {0.f, 0.f, 0.f, 0.f};   // cb1, odd kk
#pragma unroll
    for (int kk = 0; kk < 32; kk += 2) {
      bf16x8 x0 = *reinterpret_cast<const bf16x8*>(lds_h + arow + (kk + 0) * 64 + achunk);
      bf16x8 x1 = *reinterpret_cast<const bf16x8*>(lds_h + arow + (kk + 1) * 64 + achunk);
      a0 = MFMA(x0, uf0[kk + 0], a0);
      a2 = MFMA(x0, uf1[kk + 0], a2);
      a1 = MFMA(x1, uf0[kk + 1], a1);
      a3 = MFMA(x1, uf1[kk + 1], a3);
    }
    if (lane < 16) {
      f32x4 s0 = a0 + a1;
      f32x4 s1 = a2 + a3;
      zp[0][(w * 2 + 0) * 16 + lane] = s0[0];
      zp[1][(w * 2 + 0) * 16 + lane] = s0[1];
      zp[0][(w * 2 + 1) * 16 + lane] = s1[0];
      zp[1][(w * 2 + 1) * 16 + lane] = s1[1];
    }
    __syncthreads();

    // ---- gate + publish {h, tag} (first!) + out store ----
    if (tid < 32) {
      float zr[4], zi[4];
#pragma unroll
      for (int q = 0; q < 4; ++q) {
        zr[q] = zp[gb][q * 16 + gu] + brg[q] +
                bf2f((unsigned short)(zloc[q] & 0xFFFFu));
        zi[q] = zp[gb][64 + q * 16 + gu] + big[q] +
                bf2f((unsigned short)(zloc[q] >> 16));
      }
      float ar = tanh_f(zr[0]), ai = tanh_f(zi[0]);
      float ir = sigm(zr[1]), ii = sigm(zi[1]);
      float fr = sigm(zr[2]), fi = sigm(zi[2]);
      float og_r = sigm(zr[3]), og_i = sigm(zi[3]);
      float ncr = ar * ir - ai * ii + fr * cr - fi * ci;
      float nci = ar * ii + ai * ir + fr * ci + fi * cr;
      cr = ncr;
      ci = nci;
      float tr = tanh_f(cr), ti = tanh_f(ci);
      float hr = og_r * tr - og_i * ti;
      float hi = og_r * ti + og_i * tr;

      i32x2 rec;
      rec.x = (int)((unsigned)f2bf(hr) | ((unsigned)f2bf(hi) << 16));
      rec.y = t + 1;
      st8_l3(hgrp + (par ^ 1) * 8192 + (size_t)(gb * 512 + u) * 8, rec);

      float2 hv;
      hv.x = hr;
      hv.y = hi;
      *reinterpret_cast<float2*>(out + ((size_t)(bglob * T_ + t) * U_ + u) * 2) = hv;
    }
    // no trailing barrier: the tag protocol itself bounds skew to 1 step.
  }
}

// ---------------------------------------------------------------------------
extern "C" void kernel_launch(void* const* d_in, const int* in_sizes, int n_in,
                              void* d_out, int out_size, void* d_ws, size_t ws_size,
                              hipStream_t stream) {
  const float* xr = (const float*)d_in[0];
  const float* xi = (const float*)d_in[1];
  const float* Wr = (const float*)d_in[2];
  const float* Wi = (const float*)d_in[3];
  const float* Ur = (const float*)d_in[4];
  const float* Ui = (const float*)d_in[5];
  const float* br = (const float*)d_in[6];
  const float* bi = (const float*)d_in[7];

  const size_t SZ_ZX = (size_t)M_ * G4 * 2 * 2;   // 262,144,000
  const size_t SZ_AB = (size_t)M_ * KP * 2;       //  65,536,000
  const size_t SZ_BT = (size_t)JP * KP * 2;       //   8,388,608
  const size_t SZ_HB2 = (size_t)NGRP * 16384;     //     131,072
  const size_t OFF_ZX = 0;
  const size_t OFF_AB = OFF_ZX + SZ_ZX;
  const size_t OFF_BW = OFF_AB + SZ_AB;
  const size_t OFF_BU = OFF_BW + SZ_BT;
  const size_t OFF_HB = OFF_BU + SZ_BT;
  const size_t NEEDED = OFF_HB + SZ_HB2;
  if (ws_size < NEEDED) return;  // insufficient scratch

  char* ws = (char*)d_ws;
  unsigned short* zx = (unsigned short*)(ws + OFF_ZX);
  unsigned short* Ab = (unsigned short*)(ws + OFF_AB);
  unsigned short* BtW = (unsigned short*)(ws + OFF_BW);
  unsigned short* BtU = (unsigned short*)(ws + OFF_BU);
  char* hb2 = ws + OFF_HB;

  // zero h0 records {h=0, tag=0}, every launch (graph replay!)
  hipMemsetAsync(ws + OFF_HB, 0, SZ_HB2, stream);

  hipLaunchKernelGGL(k_convert_x, dim3(8000), dim3(256), 0, stream, xr, xi, Ab);
  hipLaunchKernelGGL(k_pack_B, dim3(16384), dim3(256), 0, stream, Wr, Wi, BtW);
  hipLaunchKernelGGL(k_pack_B, dim3(16384), dim3(256), 0, stream, Ur, Ui, BtU);
  hipLaunchKernelGGL(k_gemm_zx, dim3(250 * 32), dim3(256), 0, stream, Ab, BtW, zx);
  hipLaunchKernelGGL(k_scan, dim3(SCAN_BLOCKS), dim3(256), 0, stream, zx, BtU,
                     br, bi, hb2, (float*)d_out);
}

// Round 12
// 4905.605 us; speedup vs baseline: 1.4176x; 1.4176x over previous
//
#include <hip/hip_runtime.h>
#include <cstdint>
#include <cstddef>

// Problem constants
#define B_   16
#define T_   2000
#define NIN  512
#define U_   512
#define G4   2048      // 4*U
#define KP   1024      // packed K (interleaved: k' = 2*u + plane)
#define JP   4096      // packed output cols (real plane | imag plane)
#define M_   32000     // B*T
#define NGRP 8         // scan groups
#define MPG  32        // members per group
#define SCAN_BLOCKS (NGRP * MPG)
#define LDSROW 2112    // lds_h row stride (row 1 shifted to banks 16..31)
#define BKE  64        // GEMM K elements per stage step

typedef __attribute__((ext_vector_type(8))) short bf16x8;
typedef __attribute__((ext_vector_type(4))) float f32x4;
typedef __attribute__((ext_vector_type(2))) int i32x2;

typedef __attribute__((address_space(1))) const unsigned AS1U;
typedef __attribute__((address_space(3))) unsigned AS3U;

#define MFMA(a, b, c) __builtin_amdgcn_mfma_f32_16x16x32_bf16((a), (b), (c), 0, 0, 0)

__device__ __forceinline__ unsigned short f2bf(float f) {
  unsigned u = __builtin_bit_cast(unsigned, f);
  u = (u + 0x7FFFu + ((u >> 16) & 1u)) >> 16;
  return (unsigned short)u;
}
__device__ __forceinline__ float bf2f(unsigned short h) {
  unsigned u = ((unsigned)h) << 16;
  return __builtin_bit_cast(float, u);
}
__device__ __forceinline__ float sigm(float x) {
  return 1.0f / (1.0f + __expf(-x));
}
__device__ __forceinline__ float tanh_f(float x) {
  float cx = fminf(fmaxf(x, -15.0f), 15.0f);
  float e = __expf(2.0f * cx);
  return (e - 1.0f) / (e + 1.0f);
}

// --- L3-point (coherence point) accessors, rule-#18 hardened ---
__device__ __forceinline__ void ld32_l3_sync(const void* p, uint4& a, uint4& b) {
  asm volatile("global_load_dwordx4 %0, %2, off sc0 sc1\n\t"
               "global_load_dwordx4 %1, %3, off sc0 sc1\n\t"
               "s_waitcnt vmcnt(0)"
               : "=&v"(a), "=&v"(b)
               : "v"(p), "v"((const void*)((const char*)p + 16))
               : "memory");
  __builtin_amdgcn_sched_barrier(0);
}
__device__ __forceinline__ void st8_l3(void* p, i32x2 v) {
  asm volatile("global_store_dwordx2 %0, %1, off sc0 sc1" :: "v"(p), "v"(v) : "memory");
}

// ---------------------------------------------------------------------------
// Convert x fp32 [M,512]x2 -> packed A' bf16 [M,1024], k' = 2n+pl interleave.
// ---------------------------------------------------------------------------
__global__ __launch_bounds__(256) void k_convert_x(const float* __restrict__ xr,
                                                   const float* __restrict__ xi,
                                                   unsigned short* __restrict__ Ab) {
  int i = blockIdx.x * 256 + threadIdx.x;
  int m = i >> 6;
  int k0 = (i & 63) << 3;  // n-base, 8 per thread
  if (m >= M_) return;
  const float* pr = xr + (size_t)m * NIN + k0;
  const float* pi = xi + (size_t)m * NIN + k0;
  float4 r0 = *reinterpret_cast<const float4*>(pr);
  float4 r1 = *reinterpret_cast<const float4*>(pr + 4);
  float4 i0 = *reinterpret_cast<const float4*>(pi);
  float4 i1 = *reinterpret_cast<const float4*>(pi + 4);
  uint4 v0, v1;
  v0.x = f2bf(r0.x) | ((unsigned)f2bf(i0.x) << 16);
  v0.y = f2bf(r0.y) | ((unsigned)f2bf(i0.y) << 16);
  v0.z = f2bf(r0.z) | ((unsigned)f2bf(i0.z) << 16);
  v0.w = f2bf(r0.w) | ((unsigned)f2bf(i0.w) << 16);
  v1.x = f2bf(r1.x) | ((unsigned)f2bf(i1.x) << 16);
  v1.y = f2bf(r1.y) | ((unsigned)f2bf(i1.y) << 16);
  v1.z = f2bf(r1.z) | ((unsigned)f2bf(i1.z) << 16);
  v1.w = f2bf(r1.w) | ((unsigned)f2bf(i1.w) << 16);
  unsigned short* dst = Ab + (size_t)m * KP + 2 * k0;
  *reinterpret_cast<uint4*>(dst) = v0;
  *reinterpret_cast<uint4*>(dst + 8) = v1;
}

// ---------------------------------------------------------------------------
// Pack complex weight [512,2048] into Bt bf16 [4096][1024], k' = 2u+pl.
// ---------------------------------------------------------------------------
__global__ __launch_bounds__(256) void k_pack_B(const float* __restrict__ Wr,
                                                const float* __restrict__ Wi,
                                                unsigned short* __restrict__ Bt) {
  int i = blockIdx.x * 256 + threadIdx.x;
  if (i >= JP * KP) return;
  int jp = i >> 10;
  int k = i & 1023;
  int p = jp >> 11;
  int j = jp & 2047;
  int u = k >> 1;
  int pl = k & 1;
  float v;
  if (p == 0) {
    v = pl ? -Wi[(size_t)u * G4 + j] : Wr[(size_t)u * G4 + j];
  } else {
    v = pl ? Wr[(size_t)u * G4 + j] : Wi[(size_t)u * G4 + j];
  }
  Bt[i] = f2bf(v);
}

// ---------------------------------------------------------------------------
// zx GEMM v2: m97-style 128x128 tile, BK=64, global_load_lds width-16
// staging with pre-swizzled global source (col16 ^= row&7; LDS stays linear
// per m104/m173), XOR-matched ds_read_b128 fragments (bank-minimal), double-
// buffered LDS (2x(16+16)KB). K-accumulation order identical to the direct-
// load version (k=0..1024 step 32, one chain per acc elem) -> bit-identical
// output (absmax tripwire = 0.03125 exactly).
// ---------------------------------------------------------------------------
__global__ __launch_bounds__(256) void k_gemm_zx(const unsigned short* __restrict__ A,
                                                 const unsigned short* __restrict__ Bt,
                                                 unsigned short* __restrict__ zx) {
  __shared__ char AbL[2][128 * BKE * 2];  // 2 x 16KB
  __shared__ char BbL[2][128 * BKE * 2];  // 2 x 16KB

  int bid = blockIdx.x;
  int nt = bid & 31;
  int mt = bid >> 5;
  int tid = threadIdx.x;
  int lane = tid & 63;
  int wv = tid >> 6;
  int wm = wv >> 1, wn = wv & 1;
  int l15 = lane & 15;
  int kq = lane >> 4;

  // staging roles: wave wv stages rows [wv*32, wv*32+32); per inst 8 rows
  const int srow_l = lane >> 3;  // 0..7
  const int scol = lane & 7;     // 16B chunk within 128B row

  // STAGE(BUF, KT): issue 4 A + 4 B global_load_lds (1KB each) for k-step KT
#define STAGE(BUF, KT)                                                         \
  {                                                                            \
    const int k0_ = (KT)*BKE;                                                  \
    _Pragma("unroll")                                                          \
    for (int inst = 0; inst < 4; ++inst) {                                     \
      int r0_ = wv * 32 + inst * 8;                                            \
      int ra_ = r0_ + srow_l;                                                  \
      int ca_ = scol ^ (ra_ & 7);                                              \
      const unsigned short* ga_ =                                              \
          A + (size_t)(mt * 128 + ra_) * KP + k0_ + ca_ * 8;                   \
      __builtin_amdgcn_global_load_lds((AS1U*)ga_,                             \
                                       (AS3U*)&AbL[BUF][r0_ * 128], 16, 0, 0); \
      const unsigned short* gb_ =                                              \
          Bt + (size_t)(nt * 128 + ra_) * KP + k0_ + ca_ * 8;                  \
      __builtin_amdgcn_global_load_lds((AS1U*)gb_,                             \
                                       (AS3U*)&BbL[BUF][r0_ * 128], 16, 0, 0); \
    }                                                                          \
  }

  f32x4 acc[4][4];
#pragma unroll
  for (int mi = 0; mi < 4; ++mi)
#pragma unroll
    for (int ni = 0; ni < 4; ++ni) acc[mi][ni] = (f32x4){0.f, 0.f, 0.f, 0.f};

  // COMPUTE(BUF): 2 K-slices of 32, 4x4 MFMA each, swizzled fragment reads
#define COMPUTE(BUF)                                                           \
  {                                                                            \
    _Pragma("unroll")                                                          \
    for (int sl = 0; sl < 2; ++sl) {                                           \
      bf16x8 av[4], bv[4];                                                     \
      _Pragma("unroll")                                                        \
      for (int x = 0; x < 4; ++x) {                                            \
        int ra_ = wm * 64 + x * 16 + l15;                                      \
        av[x] = *reinterpret_cast<const bf16x8*>(                              \
            AbL[BUF] + ra_ * 128 + ((sl * 64 + kq * 16) ^ ((ra_ & 7) << 4)));  \
        int rb_ = wn * 64 + x * 16 + l15;                                      \
        bv[x] = *reinterpret_cast<const bf16x8*>(                              \
            BbL[BUF] + rb_ * 128 + ((sl * 64 + kq * 16) ^ ((rb_ & 7) << 4)));  \
      }                                                                        \
      _Pragma("unroll")                                                        \
      for (int mi = 0; mi < 4; ++mi)                                           \
        _Pragma("unroll")                                                      \
        for (int ni = 0; ni < 4; ++ni)                                         \
          acc[mi][ni] = MFMA(av[mi], bv[ni], acc[mi][ni]);                     \
    }                                                                          \
  }

  // prologue
  STAGE(0, 0)
  asm volatile("s_waitcnt vmcnt(0)" ::: "memory");
  __syncthreads();

  // main loop: 16 k-steps, unrolled x2 for compile-time buffer indices
  for (int kt = 0; kt < 16; kt += 2) {
    STAGE(1, kt + 1)          // kt+1 <= 15 always here
    COMPUTE(0)
    asm volatile("s_waitcnt vmcnt(0)" ::: "memory");
    __syncthreads();
    if (kt + 2 < 16) STAGE(0, kt + 2)
    COMPUTE(1)
    asm volatile("s_waitcnt vmcnt(0)" ::: "memory");
    __syncthreads();
  }
#undef STAGE
#undef COMPUTE

  // epilogue (identical to proven direct-load version)
  int rowb = mt * 128 + wm * 64;
  int colb = nt * 128 + wn * 64;
  int rq = (lane >> 4) << 2;
#pragma unroll
  for (int mi = 0; mi < 4; ++mi) {
#pragma unroll
    for (int r = 0; r < 4; ++r) {
      int m = rowb + mi * 16 + rq + r;
      int bbv = m / T_;
      int tv = m - bbv * T_;
      size_t rowoff = (size_t)(tv * 16 + bbv) * (G4 * 2);
#pragma unroll
      for (int ni = 0; ni < 4; ++ni) {
        int jp2 = colb + ni * 16 + l15;
        int p = jp2 >> 11;
        int j = jp2 & 2047;
        zx[rowoff + (size_t)j * 2 + p] = f2bf(acc[mi][ni][r]);
      }
    }
  }
}

// ---------------------------------------------------------------------------
// Persistent scan v8 (RESTORED byte-exact — proven 4.58ms, absmax 0.03125).
// Tag-fused barrier on the L3 path, no prologue. 256 blocks x 512 threads.
// Group g = bid&7 owns batches {2g,2g+1}; member m = bid>>3 owns units
// [16m,16m+16) -> 128 jp-rows of U pinned in registers. h exchange:
// [g][par][gb*512+u] 8B records {h bf16x2, tag=t+1}; 256 stager threads poll
// 32B chunks until tags >= t -- the successful poll IS the stage load.
// ---------------------------------------------------------------------------
__global__ __launch_bounds__(512, 2) void k_scan(
    const unsigned short* __restrict__ zx,
    const unsigned short* __restrict__ Ub,
    const float* __restrict__ brp,
    const float* __restrict__ bip,
    char* __restrict__ hb2,   // [NGRP][2 par][1024 records][8B]
    float* __restrict__ out) {
  const int bid = blockIdx.x;
  const int tid = threadIdx.x;
  const int lane = tid & 63;
  const int w = tid >> 6;
  const int l15 = lane & 15;
  const int g = bid & 7;
  const int m = bid >> 3;

  __shared__ char lds_h[2 * LDSROW];  // [2 batch rows][2048B h], stride 2112
  __shared__ float zp[2][132];        // z exchange [batch][row]

  // ---- U fragments: wave w -> (plane p_=w>>2, gate q_=w&3), 16 units ----
  const int p_ = w >> 2, q_ = w & 3;
  const unsigned short* uptr =
      Ub + (size_t)(p_ * 2048 + q_ * 512 + m * 16 + l15) * KP + ((lane >> 4) << 3);
  bf16x8 uf[32];
#pragma unroll
  for (int kk = 0; kk < 32; ++kk)
    uf[kk] = *reinterpret_cast<const bf16x8*>(uptr + kk * 32);
#pragma unroll
  for (int kk = 0; kk < 32; ++kk)
    asm volatile("" : "+v"(uf[kk]));  // pin against rematerialization

  // ---- gate mapping (threads 0..31) ----
  const int gb = tid >> 4;        // local batch 0..1
  const int gu = tid & 15;        // local unit 0..15
  const int u = m * 16 + gu;      // global unit
  const int bglob = g * 2 + gb;   // global batch
  float brg[4], big[4];
  if (tid < 32) {
#pragma unroll
    for (int q = 0; q < 4; ++q) {
      brg[q] = brp[q * 512 + u];
      big[q] = bip[q * 512 + u];
    }
  }
  float cr = 0.f, ci = 0.f;

  char* hgrp = hb2 + (size_t)g * 16384;

  // ---- stager mapping (threads 0..255): 32B = records 4*tid .. 4*tid+3 ----
  const int srow = tid >> 7;            // batch row 0..1
  const int sbyte = (tid & 127) * 16;   // LDS byte offset in row

  // ---- A-fragment read addressing (conflict-free: rows split banks) ----
  const int arow = (l15 & 1) * LDSROW;
  const int achunk = (lane >> 4) * 16;

  // ---- zx prologue (1-step-ahead prefetch) ----
  unsigned zprev[4];
  if (tid < 32) {
    const unsigned* zt = (const unsigned*)zx + (size_t)bglob * 2048;
#pragma unroll
    for (int q = 0; q < 4; ++q) zprev[q] = zt[q * 512 + u];
  }

  for (int t = 0; t < T_; ++t) {
    const int par = t & 1;

    // ---- stage: poll own 32B (4 records) until tags >= t; poll IS load ----
    if (tid < 256) {
      const char* src = hgrp + par * 8192 + tid * 32;
      uint4 v0, v1;
      for (;;) {
        ld32_l3_sync(src, v0, v1);   // data valid at return (rule #18 fix)
        if ((int)v0.y >= t && (int)v0.w >= t &&
            (int)v1.y >= t && (int)v1.w >= t) break;
        __builtin_amdgcn_s_sleep(1);
      }
      uint4 hq;
      hq.x = v0.x;
      hq.y = v0.z;
      hq.z = v1.x;
      hq.w = v1.z;
      *reinterpret_cast<uint4*>(lds_h + srow * LDSROW + sbyte) = hq;
    }
    __syncthreads();

    // ---- consume z(t); issue z(t+1) early ----
    unsigned zloc[4];
    if (tid < 32) {
#pragma unroll
      for (int q = 0; q < 4; ++q) zloc[q] = zprev[q];
      int tp = t + 1 < T_ ? t + 1 : t;
      const unsigned* zt = (const unsigned*)zx + (size_t)(tp * 16 + bglob) * 2048;
#pragma unroll
      for (int q = 0; q < 4; ++q) zprev[q] = zt[q * 512 + u];
    }

    // ---- MFMA: 32 k-iters, 4 chains, conflict-free A reads ----
    f32x4 a0 = {0.f, 0.f, 0.f, 0.f};
    f32x4 a1 = {0.f, 0.f, 0.f, 0.f};
    f32x4 a2 = {0.f, 0.f, 0.f, 0.f};
    f32x4 a3 = {0.f, 0.f, 0.f, 0.f};
#pragma unroll
    for (int kk = 0; kk < 32; kk += 4) {
      bf16x8 x0 = *reinterpret_cast<const bf16x8*>(lds_h + arow + (kk + 0) * 64 + achunk);
      bf16x8 x1 = *reinterpret_cast<const bf16x8*>(lds_h + arow + (kk + 1) * 64 + achunk);
      bf16x8 x2 = *reinterpret_cast<const bf16x8*>(lds_h + arow + (kk + 2) * 64 + achunk);
      bf16x8 x3 = *reinterpret_cast<const bf16x8*>(lds_h + arow + (kk + 3) * 64 + achunk);
      a0 = MFMA(x0, uf[kk + 0], a0);
      a1 = MFMA(x1, uf[kk + 1], a1);
      a2 = MFMA(x2, uf[kk + 2], a2);
      a3 = MFMA(x3, uf[kk + 3], a3);
    }
    if (lane < 16) {
      f32x4 s = (a0 + a1) + (a2 + a3);
      zp[0][w * 16 + lane] = s[0];
      zp[1][w * 16 + lane] = s[1];
    }
    __syncthreads();

    // ---- gate + publish {h, tag} (first!) + out store ----
    if (tid < 32) {
      float zr[4], zi[4];
#pragma unroll
      for (int q = 0; q < 4; ++q) {
        zr[q] = zp[gb][q * 16 + gu] + brg[q] +
                bf2f((unsigned short)(zloc[q] & 0xFFFFu));
        zi[q] = zp[gb][64 + q * 16 + gu] + big[q] +
                bf2f((unsigned short)(zloc[q] >> 16));
      }
      float ar = tanh_f(zr[0]), ai = tanh_f(zi[0]);
      float ir = sigm(zr[1]), ii = sigm(zi[1]);
      float fr = sigm(zr[2]), fi = sigm(zi[2]);
      float og_r = sigm(zr[3]), og_i = sigm(zi[3]);
      float ncr = ar * ir - ai * ii + fr * cr - fi * ci;
      float nci = ar * ii + ai * ir + fr * ci + fi * cr;
      cr = ncr;
      ci = nci;
      float tr = tanh_f(cr), ti = tanh_f(ci);
      float hr = og_r * tr - og_i * ti;
      float hi = og_r * ti + og_i * tr;

      i32x2 rec;
      rec.x = (int)((unsigned)f2bf(hr) | ((unsigned)f2bf(hi) << 16));
      rec.y = t + 1;
      st8_l3(hgrp + (par ^ 1) * 8192 + (size_t)(gb * 512 + u) * 8, rec);

      float2 hv;
      hv.x = hr;
      hv.y = hi;
      *reinterpret_cast<float2*>(out + ((size_t)(bglob * T_ + t) * U_ + u) * 2) = hv;
    }
    // no trailing barrier: the tag protocol itself bounds skew to 1 step.
  }
}

// ---------------------------------------------------------------------------
extern "C" void kernel_launch(void* const* d_in, const int* in_sizes, int n_in,
                              void* d_out, int out_size, void* d_ws, size_t ws_size,
                              hipStream_t stream) {
  const float* xr = (const float*)d_in[0];
  const float* xi = (const float*)d_in[1];
  const float* Wr = (const float*)d_in[2];
  const float* Wi = (const float*)d_in[3];
  const float* Ur = (const float*)d_in[4];
  const float* Ui = (const float*)d_in[5];
  const float* br = (const float*)d_in[6];
  const float* bi = (const float*)d_in[7];

  const size_t SZ_ZX = (size_t)M_ * G4 * 2 * 2;   // 262,144,000
  const size_t SZ_AB = (size_t)M_ * KP * 2;       //  65,536,000
  const size_t SZ_BT = (size_t)JP * KP * 2;       //   8,388,608
  const size_t SZ_HB2 = (size_t)NGRP * 16384;     //     131,072
  const size_t OFF_ZX = 0;
  const size_t OFF_AB = OFF_ZX + SZ_ZX;
  const size_t OFF_BW = OFF_AB + SZ_AB;
  const size_t OFF_BU = OFF_BW + SZ_BT;
  const size_t OFF_HB = OFF_BU + SZ_BT;
  const size_t NEEDED = OFF_HB + SZ_HB2;
  if (ws_size < NEEDED) return;  // insufficient scratch

  char* ws = (char*)d_ws;
  unsigned short* zx = (unsigned short*)(ws + OFF_ZX);
  unsigned short* Ab = (unsigned short*)(ws + OFF_AB);
  unsigned short* BtW = (unsigned short*)(ws + OFF_BW);
  unsigned short* BtU = (unsigned short*)(ws + OFF_BU);
  char* hb2 = ws + OFF_HB;

  // zero h0 records {h=0, tag=0}, every launch (graph replay!)
  hipMemsetAsync(ws + OFF_HB, 0, SZ_HB2, stream);

  hipLaunchKernelGGL(k_convert_x, dim3(8000), dim3(256), 0, stream, xr, xi, Ab);
  hipLaunchKernelGGL(k_pack_B, dim3(16384), dim3(256), 0, stream, Wr, Wi, BtW);
  hipLaunchKernelGGL(k_pack_B, dim3(16384), dim3(256), 0, stream, Ur, Ui, BtU);
  hipLaunchKernelGGL(k_gemm_zx, dim3(250 * 32), dim3(256), 0, stream, Ab, BtW, zx);
  hipLaunchKernelGGL(k_scan, dim3(SCAN_BLOCKS), dim3(512), 0, stream, zx, BtU,
                     br, bi, hb2, (float*)d_out);
}